// Round 3
// baseline (406.175 us; speedup 1.0000x reference)
//
#include <hip/hip_runtime.h>
#include <float.h>

// Problem constants
#define NB    16
#define DIM   512
#define HW    1024        // 32*32
#define NCB   8
#define VOC   1024
#define DCB   64

#define THREADS   256
#define POS_TILE  128
#define VCHUNK    128
#define NCHUNK    (VOC / VCHUNK)   // 8
#define NK4       16               // 64 dims / 4
#define CAP       16
#define MARGIN    5e-4f
#define SLAB      516              // dwords per k4 slab: 128 elems * 4 + 4 pad

// LDS layout (dwords)
#define ZS_OFF    0
#define CS_OFF    (ZS_OFF + NK4 * SLAB)        // 8256
#define CI_OFF    (CS_OFF + NK4 * SLAB)        // 16512
#define CNT_OFF   (CI_OFF + POS_TILE * CAP)    // 18560
#define IDXF_OFF  (CNT_OFF + POS_TILE)         // 18688
#define WRED_OFF  (IDXF_OFF + POS_TILE)        // 18816
#define ZZ_OFF    (WRED_OFF + 8)               // 18824
#define LDS_DW    (ZZ_OFF + POS_TILE)          // 18952 -> 75808 bytes

#define Q_ELEMS   8388608
#define I_ELEMS   131072
#define C_OFFSET  (Q_ELEMS + I_ELEMS)          // 8519680

// ===== numpy-f32 emulation helpers =====
// np.sum(v*v, axis=-1) for 64 contiguous f32: squares rounded to f32, then
// numpy pairwise_sum (n<=128 path): 8 accumulators + fixed tree.
__device__ __forceinline__ float np_sumsq64(const float v[64]) {
#pragma clang fp contract(off)
    float sq[64];
#pragma unroll
    for (int k = 0; k < 64; ++k) sq[k] = v[k] * v[k];
    float r[8];
#pragma unroll
    for (int j = 0; j < 8; ++j) r[j] = sq[j];
#pragma unroll
    for (int i = 8; i < 64; i += 8)
#pragma unroll
        for (int j = 0; j < 8; ++j) r[j] = r[j] + sq[i + j];
    return ((r[0] + r[1]) + (r[2] + r[3])) + ((r[4] + r[5]) + (r[6] + r[7]));
}

// np.einsum f32 dot of 64 elems (contig_contig_outstride0_two, AVX512):
// 16 SIMD lanes, chained FMA over 4 chunks, npyv_sum_f32 tree (8,4,2,1);
// then dists = (zz - 2*E) + cc elementwise f32, left-to-right.
__device__ __forceinline__ float np_dist(const float zloc[64], const float c[64],
                                         float zz, float ccv) {
#pragma clang fp contract(off)
    float p[16];
#pragma unroll
    for (int l = 0; l < 16; ++l) p[l] = 0.f;
#pragma unroll
    for (int j = 0; j < 4; ++j)
#pragma unroll
        for (int l = 0; l < 16; ++l)
            p[l] = __builtin_fmaf(zloc[j * 16 + l], c[j * 16 + l], p[l]);
    float s8[8], s4[4];
#pragma unroll
    for (int l = 0; l < 8; ++l) s8[l] = p[l] + p[l + 8];
#pragma unroll
    for (int l = 0; l < 4; ++l) s4[l] = s8[l] + s8[l + 4];
    float u0 = s4[0] + s4[2];
    float u1 = s4[1] + s4[3];
    float E  = u0 + u1;
    float t  = zz - 2.0f * E;
    return t + ccv;
}

// ---- K0: per-code np-emulated squared norms into workspace ----
__global__ __launch_bounds__(256) void vq_cc_kernel(const float* __restrict__ cbk,
                                                    float* __restrict__ cc) {
    int g = blockIdx.x * 256 + threadIdx.x;    // 0..8191 = cb*1024 + v
    const float4* row = (const float4*)(cbk + (long)g * DCB);
    float c[64];
#pragma unroll
    for (int i = 0; i < 16; ++i) {
        float4 v = row[i];
        c[i * 4 + 0] = v.x; c[i * 4 + 1] = v.y;
        c[i * 4 + 2] = v.z; c[i * 4 + 3] = v.w;
    }
    cc[g] = np_sumsq64(c);
}

// ---- K1: main scan + np-exact refine + outputs ----
__global__ __launch_bounds__(THREADS, 2) void vq_main_kernel(
    const float* __restrict__ z, const float* __restrict__ cbk,
    const float* __restrict__ ccTab, float* __restrict__ commitWs,
    float* __restrict__ out)
{
    extern __shared__ float lds[];
    float*        zs    = lds + ZS_OFF;        // later reused as f32 q tile [k][pos]
    float*        cs    = lds + CS_OFF;
    unsigned*     candI = (unsigned*)(lds + CI_OFF);
    unsigned*     cnt   = (unsigned*)(lds + CNT_OFF);
    unsigned*     idxF  = (unsigned*)(lds + IDXF_OFF);
    float*        wred  = lds + WRED_OFF;
    float*        zzS   = lds + ZZ_OFF;

    const int tid  = threadIdx.x;
    const int tcol = tid & 15;
    const int trow = tid >> 4;            // 0..15
    const int cb   = blockIdx.x & 7;
    const int tile = blockIdx.x >> 3;     // 0..127
    const int b    = tile >> 3;           // 8 tiles per batch (1024/128)
    const int hw0  = (tile & 7) * POS_TILE;

    const long zBase  = (long)b * (DIM * HW) + (long)cb * DCB * HW + hw0;
    const long cbBase = (long)cb * (VOC * DCB);
    const float* ccRow = ccTab + cb * VOC;

    // ---- stage z tile: 64 k x 128 pos, interleaved [k4][pos][4] ----
    for (int i = 0; i < 32; ++i) {
        int e   = i * THREADS + tid;      // 0..8191
        int k   = e >> 7;
        int pos = e & 127;
        float v = z[zBase + (long)k * HW + pos];
        zs[(k >> 2) * SLAB + pos * 4 + (k & 3)] = v;
    }
    if (tid < POS_TILE) cnt[tid] = 0;
    __syncthreads();

    // ---- np-emulated zz per pos ----
    if (tid < POS_TILE) {
        float zloc[64];
#pragma unroll
        for (int k = 0; k < 64; ++k)
            zloc[k] = zs[(k >> 2) * SLAB + tid * 4 + (k & 3)];
        zzS[tid] = np_sumsq64(zloc);
    }

    float    runBest[8];
    unsigned runIdx[8];
#pragma unroll
    for (int p = 0; p < 8; ++p) { runBest[p] = FLT_MAX; runIdx[p] = 0xFFFFFFFFu; }

    for (int chunk = 0; chunk < NCHUNK; ++chunk) {
        __syncthreads();   // cs safe to overwrite
        {   // stage codebook chunk: 128 codes x 64 dims
            const float4* src = (const float4*)(cbk + cbBase + (long)chunk * VCHUNK * DCB);
#pragma unroll
            for (int i = 0; i < 8; ++i) {
                int f   = i * THREADS + tid;   // float4 idx 0..2047
                int voc = f >> 4;
                int k4  = f & 15;
                float4 v = src[f];
                *(float4*)(cs + k4 * SLAB + voc * 4) = v;
            }
        }
        __syncthreads();

        float acc[8][8];
#pragma unroll
        for (int p = 0; p < 8; ++p)
#pragma unroll
            for (int j = 0; j < 8; ++j) acc[p][j] = 0.f;

        for (int k4 = 0; k4 < NK4; ++k4) {
            float4 zf[8], cf[8];
#pragma unroll
            for (int p = 0; p < 8; ++p)
                zf[p] = *(const float4*)(zs + k4 * SLAB + (p * 16 + trow) * 4);
#pragma unroll
            for (int j = 0; j < 8; ++j)
                cf[j] = *(const float4*)(cs + k4 * SLAB + (j * 16 + tcol) * 4);
#pragma unroll
            for (int p = 0; p < 8; ++p)
#pragma unroll
                for (int j = 0; j < 8; ++j) {
                    acc[p][j] = fmaf(zf[p].x, cf[j].x, acc[p][j]);
                    acc[p][j] = fmaf(zf[p].y, cf[j].y, acc[p][j]);
                    acc[p][j] = fmaf(zf[p].z, cf[j].z, acc[p][j]);
                    acc[p][j] = fmaf(zf[p].w, cf[j].w, acc[p][j]);
                }
        }

        // scan metric d' = cc - 2*dot (zz dropped); argmin + margin appends
        float ccv[8];
#pragma unroll
        for (int j = 0; j < 8; ++j) ccv[j] = ccRow[chunk * VCHUNK + j * 16 + tcol];

#pragma unroll
        for (int p = 0; p < 8; ++p) {
            float bd = FLT_MAX; unsigned bi = 0xFFFFFFFFu;
#pragma unroll
            for (int j = 0; j < 8; ++j) {
                float d = fmaf(-2.f, acc[p][j], ccv[j]);
                acc[p][j] = d;
                unsigned vi = chunk * VCHUNK + j * 16 + tcol;
                if (d < bd || (d == bd && vi < bi)) { bd = d; bi = vi; }
            }
#pragma unroll
            for (int m = 1; m < 16; m <<= 1) {
                float    od = __shfl_xor(bd, m, 64);
                unsigned oi = __shfl_xor(bi, m, 64);
                if (od < bd || (od == bd && oi < bi)) { bd = od; bi = oi; }
            }
            if (bd < runBest[p] || (bd == runBest[p] && bi < runIdx[p])) {
                runBest[p] = bd; runIdx[p] = bi;
            }
            const float thr = runBest[p] + MARGIN;
            const int pos = p * 16 + trow;
#pragma unroll
            for (int j = 0; j < 8; ++j) {
                if (acc[p][j] <= thr) {
                    unsigned slot = atomicAdd(&cnt[pos], 1u);
                    if (slot < CAP) candI[pos * CAP + slot] = chunk * VCHUNK + j * 16 + tcol;
                }
            }
        }
    }
    __syncthreads();

    // ---- np-exact f32 refine of candidates; group = 16 tcol lanes ----
    for (int p = 0; p < 8; ++p) {
        const int pos = p * 16 + trow;
        float zloc[64];
#pragma unroll
        for (int k = 0; k < 64; ++k)
            zloc[k] = zs[(k >> 2) * SLAB + pos * 4 + (k & 3)];   // broadcast reads
        const float zz = zzS[pos];
        const unsigned n = cnt[pos];
        float bd = FLT_MAX; unsigned bi = 0xFFFFFFFFu;
        if (n <= CAP) {
            for (unsigned s = tcol; s < n; s += 16) {
                unsigned vi = candI[pos * CAP + s];
                const float4* cr = (const float4*)(cbk + cbBase + (long)vi * DCB);
                float c[64];
#pragma unroll
                for (int i = 0; i < 16; ++i) {
                    float4 v = cr[i];
                    c[i * 4 + 0] = v.x; c[i * 4 + 1] = v.y;
                    c[i * 4 + 2] = v.z; c[i * 4 + 3] = v.w;
                }
                float d = np_dist(zloc, c, zz, ccRow[vi]);
                if (d < bd || (d == bd && vi < bi)) { bd = d; bi = vi; }
            }
        } else {  // overflow fallback: np-exact rescan of all 1024
            for (unsigned vi = tcol; vi < VOC; vi += 16) {
                const float4* cr = (const float4*)(cbk + cbBase + (long)vi * DCB);
                float c[64];
#pragma unroll
                for (int i = 0; i < 16; ++i) {
                    float4 v = cr[i];
                    c[i * 4 + 0] = v.x; c[i * 4 + 1] = v.y;
                    c[i * 4 + 2] = v.z; c[i * 4 + 3] = v.w;
                }
                float d = np_dist(zloc, c, zz, ccRow[vi]);
                if (d < bd || (d == bd && vi < bi)) { bd = d; bi = vi; }
            }
        }
#pragma unroll
        for (int m = 1; m < 16; m <<= 1) {
            float    od = __shfl_xor(bd, m, 64);
            unsigned oi = __shfl_xor(bi, m, 64);
            if (od < bd || (od == bd && oi < bi)) { bd = od; bi = oi; }
        }
        if (tcol == 0) idxF[pos] = bi;
    }
    __syncthreads();

    // ---- indices output (f32 of integer index) ----
    if (tid < POS_TILE) {
        unsigned vi = idxF[tid];
        out[Q_ELEMS + (long)b * (NCB * HW) + cb * HW + hw0 + tid] = (float)vi;
    }

    // ---- G1: gather q into registers, commitment partials ----
    float qreg[32];
    {
        const int pos   = tid & 127;
        const int khalf = tid >> 7;      // 0..1, 32 dims each
        const unsigned vi = idxF[pos];
        const float* crow = cbk + cbBase + (long)vi * DCB + khalf * 32;
        float csum = 0.f;
#pragma unroll
        for (int j4 = 0; j4 < 8; ++j4) {
            const int k4 = khalf * 8 + j4;
            float4 zf = *(const float4*)(zs + k4 * SLAB + pos * 4);
            float4 cv = *(const float4*)(crow + j4 * 4);
            // q_st = (q - z) + z, matching reference rounding
            qreg[j4 * 4 + 0] = (cv.x - zf.x) + zf.x;
            qreg[j4 * 4 + 1] = (cv.y - zf.y) + zf.y;
            qreg[j4 * 4 + 2] = (cv.z - zf.z) + zf.z;
            qreg[j4 * 4 + 3] = (cv.w - zf.w) + zf.w;
            float d0 = zf.x - cv.x; csum = fmaf(d0, d0, csum);
            float d1 = zf.y - cv.y; csum = fmaf(d1, d1, csum);
            float d2 = zf.z - cv.z; csum = fmaf(d2, d2, csum);
            float d3 = zf.w - cv.w; csum = fmaf(d3, d3, csum);
        }
#pragma unroll
        for (int m = 1; m < 64; m <<= 1) csum += __shfl_xor(csum, m, 64);
        if ((tid & 63) == 0) wred[tid >> 6] = csum;
    }
    __syncthreads();   // all reads of zs (refine, G1) done; wred visible

    // ---- G2: overwrite zs region with f32 q tile [k][pos] ----
    {
        const int pos   = tid & 127;
        const int khalf = tid >> 7;
#pragma unroll
        for (int j = 0; j < 32; ++j)
            zs[(khalf * 32 + j) * POS_TILE + pos] = qreg[j];
    }
    __syncthreads();
    if (tid == 0) atomicAdd(commitWs, wred[0] + wred[1] + wred[2] + wred[3]);

    // ---- G3: quantized output, coalesced float4 stores ----
    {
        const int k    = tid >> 2;       // 0..63
        const int part = tid & 3;        // 0..3 -> 32 positions each
        const float* srcq = zs + k * POS_TILE + part * 32;
        long off = (long)b * (DIM * HW) + (long)(cb * DCB + k) * HW + hw0 + part * 32;
        float4* dst = (float4*)(out + off);
#pragma unroll
        for (int i = 0; i < 8; ++i)
            dst[i] = *(const float4*)(srcq + i * 4);
    }
}

// ---- K2: finalize commitment scalar ----
__global__ void vq_fin_kernel(const float* __restrict__ ws, float* __restrict__ out) {
    out[C_OFFSET] = ws[0] * (1.0f / 8388608.0f);
}

extern "C" void kernel_launch(void* const* d_in, const int* in_sizes, int n_in,
                              void* d_out, int out_size, void* d_ws, size_t ws_size,
                              hipStream_t stream) {
    (void)in_sizes; (void)n_in; (void)out_size; (void)ws_size;
    const float* z   = (const float*)d_in[0];
    const float* cbk = (const float*)d_in[1];
    float* out   = (float*)d_out;
    float* ws    = (float*)d_ws;       // [0]: commitment accumulator
    float* ccTab = ws + 64;            // byte offset 256: 8192 f32 code norms

    hipMemsetAsync(d_ws, 0, 4, stream);
    vq_cc_kernel<<<dim3(32), dim3(256), 0, stream>>>(cbk, ccTab);
    vq_main_kernel<<<dim3(1024), dim3(THREADS), LDS_DW * 4, stream>>>(z, cbk, ccTab, ws, out);
    vq_fin_kernel<<<dim3(1), dim3(1), 0, stream>>>(ws, out);
}

// Round 4
// 251.817 us; speedup vs baseline: 1.6130x; 1.6130x over previous
//
#include <hip/hip_runtime.h>
#include <float.h>

// Problem constants
#define NBATCH 16
#define DIM   512
#define HW    1024
#define NCB   8
#define VOC   1024
#define DCB   64

#define THREADS   256
#define POS_TILE  128
#define VCHUNK    128
#define NCHUNK    8
#define CAP       8
#define MARGIN    0.015f

#define Q_ELEMS   8388608
#define I_ELEMS   131072
#define C_OFFSET  8519680

// LDS byte offsets
#define ZSB_OFF   0          // ushort[128][64]  16384  (bf16 z, swizzled)
#define CSB_OFF   16384      // ushort[128][64]  16384  (bf16 codes, swizzled)
#define CCS_OFF   32768      // float[1024]      4096   (cc row for this cb)
#define BD_OFF    36864      // uint[128]        512    (scan-min, monotone key)
#define CI_OFF    37376      // uint[128*8]      4096   (candidates)
#define CNT_OFF   41472      // uint[128]        512
#define IDXF_OFF  41984      // uint[128]        512
#define ZZ_OFF    42496      // float[128]       512
#define WR_OFF    43008      // float[8]         32
#define LDS_BYTES 43040

typedef __attribute__((ext_vector_type(8))) short    short8;
typedef __attribute__((ext_vector_type(8))) unsigned short ushort8;
typedef __attribute__((ext_vector_type(4))) float    floatx4;

// f32 -> bf16 RNE (deterministic; error absorbed by MARGIN)
__device__ __forceinline__ unsigned short f2bf(float f) {
    unsigned u = __builtin_bit_cast(unsigned, f);
    unsigned r = u + 0x7FFFu + ((u >> 16) & 1u);
    return (unsigned short)(r >> 16);
}
// monotone uint key for float (handles negatives) and inverse
__device__ __forceinline__ unsigned fkey(float f) {
    unsigned u = __builtin_bit_cast(unsigned, f);
    return (u & 0x80000000u) ? ~u : (u | 0x80000000u);
}
__device__ __forceinline__ float funkey(unsigned k) {
    unsigned u = (k & 0x80000000u) ? (k & 0x7FFFFFFFu) : ~k;
    return __builtin_bit_cast(float, u);
}

// ===== numpy-f32 emulation (identical arithmetic to round-3 PASSING kernel) =====
__device__ __forceinline__ float np_sumsq64(const float v[64]) {
#pragma clang fp contract(off)
    float sq[64];
#pragma unroll
    for (int k = 0; k < 64; ++k) sq[k] = v[k] * v[k];
    float r[8];
#pragma unroll
    for (int j = 0; j < 8; ++j) r[j] = sq[j];
#pragma unroll
    for (int i = 8; i < 64; i += 8)
#pragma unroll
        for (int j = 0; j < 8; ++j) r[j] = r[j] + sq[i + j];
    return ((r[0] + r[1]) + (r[2] + r[3])) + ((r[4] + r[5]) + (r[6] + r[7]));
}

__device__ __forceinline__ float np_sumsq64_strided(const float* p, int stride) {
#pragma clang fp contract(off)
    float r[8];
#pragma unroll
    for (int j = 0; j < 8; ++j) { float v = p[(long)j * stride]; r[j] = v * v; }
#pragma unroll
    for (int i = 1; i < 8; ++i)
#pragma unroll
        for (int j = 0; j < 8; ++j) {
            float v = p[(long)(i * 8 + j) * stride];
            r[j] = r[j] + v * v;
        }
    return ((r[0] + r[1]) + (r[2] + r[3])) + ((r[4] + r[5]) + (r[6] + r[7]));
}

__device__ __forceinline__ float np_dist(const float zloc[64], const float c[64],
                                         float zz, float ccv) {
#pragma clang fp contract(off)
    float p[16];
#pragma unroll
    for (int l = 0; l < 16; ++l) p[l] = 0.f;
#pragma unroll
    for (int j = 0; j < 4; ++j)
#pragma unroll
        for (int l = 0; l < 16; ++l)
            p[l] = __builtin_fmaf(zloc[j * 16 + l], c[j * 16 + l], p[l]);
    float s8[8], s4[4];
#pragma unroll
    for (int l = 0; l < 8; ++l) s8[l] = p[l] + p[l + 8];
#pragma unroll
    for (int l = 0; l < 4; ++l) s4[l] = s8[l] + s8[l + 4];
    float u0 = s4[0] + s4[2];
    float u1 = s4[1] + s4[3];
    float E  = u0 + u1;
    float t  = zz - 2.0f * E;
    return t + ccv;
}

// ---- K0: per-code np-emulated squared norms ----
__global__ __launch_bounds__(256) void vq_cc_kernel(const float* __restrict__ cbk,
                                                    float* __restrict__ cc) {
    int g = blockIdx.x * 256 + threadIdx.x;
    const float4* row = (const float4*)(cbk + (long)g * DCB);
    float c[64];
#pragma unroll
    for (int i = 0; i < 16; ++i) {
        float4 v = row[i];
        c[i * 4 + 0] = v.x; c[i * 4 + 1] = v.y;
        c[i * 4 + 2] = v.z; c[i * 4 + 3] = v.w;
    }
    cc[g] = np_sumsq64(c);
}

// ---- K1: MFMA scan (2-pass) + np-exact refine + outputs ----
__global__ __launch_bounds__(THREADS, 3) void vq_main_kernel(
    const float* __restrict__ z, const float* __restrict__ cbk,
    const float* __restrict__ ccTab, float* __restrict__ commitWs,
    float* __restrict__ out)
{
    extern __shared__ char lds[];
    unsigned short* zsb   = (unsigned short*)(lds + ZSB_OFF);
    unsigned short* csb   = (unsigned short*)(lds + CSB_OFF);
    float*          ccS   = (float*)(lds + CCS_OFF);
    unsigned*       bestU = (unsigned*)(lds + BD_OFF);
    unsigned*       candI = (unsigned*)(lds + CI_OFF);
    unsigned*       cnt   = (unsigned*)(lds + CNT_OFF);
    unsigned*       idxF  = (unsigned*)(lds + IDXF_OFF);
    float*          zzS   = (float*)(lds + ZZ_OFF);
    float*          wred  = (float*)(lds + WR_OFF);

    const int tid  = threadIdx.x;
    const int lane = tid & 63;
    const int wid  = tid >> 6;          // 4 waves
    const int wr   = wid >> 1;          // pos half (0..1)
    const int wc   = wid & 1;           // code half (0..1)
    const int cb   = blockIdx.x & 7;
    const int tile = blockIdx.x >> 3;
    const int b    = tile >> 3;
    const int hw0  = (tile & 7) * POS_TILE;

    const long zBase  = (long)b * (DIM * HW) + (long)cb * DCB * HW + hw0;
    const long cbBase = (long)cb * (VOC * DCB);

    // ---- stage z as bf16 [pos][k] with (pos&7)<<3 ushort-XOR swizzle ----
    for (int i = 0; i < 32; ++i) {
        int e   = i * THREADS + tid;
        int k   = e >> 7;
        int pos = e & 127;
        float v = z[zBase + (long)k * HW + pos];
        zsb[pos * 64 + (k ^ ((pos & 7) << 3))] = f2bf(v);
    }
    // ---- stage cc row ----
    {
        const float4* src = (const float4*)(ccTab + cb * VOC);
        float4* dst = (float4*)ccS;
#pragma unroll
        for (int i = 0; i < 1; ++i) { }  // (kept simple below)
        dst[tid] = src[tid];                     // 256 float4 = 1024 floats
    }
    if (tid < POS_TILE) { cnt[tid] = 0; bestU[tid] = 0xFFFFFFFFu; }
    // ---- np-emulated zz per pos (from global f32 z) ----
    if (tid < POS_TILE) {
        zzS[tid] = np_sumsq64_strided(z + zBase + tid, HW);
    }

    // per-lane fragment constants
    const int l15   = lane & 15;
    const int lg    = lane >> 4;        // k-group for A/B, row-group for C
    const int zrow0 = wr * 64 + l15;    // A row (pos), + pt*16
    const int crow0 = wc * 64 + l15;    // B row (code), + ct*16
    const int sA    = (zrow0 & 7) << 3;
    const int sB    = (crow0 & 7) << 3;
    const int kb    = lg * 8;

    float mn[4][4];
    float thr[4][4];
#pragma unroll
    for (int pt = 0; pt < 4; ++pt)
#pragma unroll
        for (int r = 0; r < 4; ++r) { mn[pt][r] = FLT_MAX; thr[pt][r] = 0.f; }

    for (int pass = 0; pass < 2; ++pass) {
        for (int chunk = 0; chunk < NCHUNK; ++chunk) {
            __syncthreads();   // previous reads of csb done
            {   // stage codebook chunk bf16 [code][k] swizzled
                const float* src = cbk + cbBase + (long)chunk * VCHUNK * DCB;
#pragma unroll
                for (int g = 0; g < 4; ++g) {
                    int e    = g * THREADS + tid;   // 8-elem group
                    int code = e >> 3;
                    int kg   = e & 7;
                    float4 v0 = *(const float4*)(src + e * 8);
                    float4 v1 = *(const float4*)(src + e * 8 + 4);
                    ushort8 w;
                    w[0] = f2bf(v0.x); w[1] = f2bf(v0.y);
                    w[2] = f2bf(v0.z); w[3] = f2bf(v0.w);
                    w[4] = f2bf(v1.x); w[5] = f2bf(v1.y);
                    w[6] = f2bf(v1.z); w[7] = f2bf(v1.w);
                    *(ushort8*)&csb[code * 64 + ((kg * 8) ^ ((code & 7) << 3))] = w;
                }
            }
            __syncthreads();

            floatx4 acc[4][4];
#pragma unroll
            for (int pt = 0; pt < 4; ++pt)
#pragma unroll
                for (int ct = 0; ct < 4; ++ct)
                    acc[pt][ct] = floatx4{0.f, 0.f, 0.f, 0.f};

#pragma unroll
            for (int ks = 0; ks < 2; ++ks) {
                short8 af[4], bf[4];
#pragma unroll
                for (int pt = 0; pt < 4; ++pt)
                    af[pt] = *(const short8*)&zsb[(zrow0 + pt * 16) * 64 + ((ks * 32 + kb) ^ sA)];
#pragma unroll
                for (int ct = 0; ct < 4; ++ct)
                    bf[ct] = *(const short8*)&csb[(crow0 + ct * 16) * 64 + ((ks * 32 + kb) ^ sB)];
#pragma unroll
                for (int pt = 0; pt < 4; ++pt)
#pragma unroll
                    for (int ct = 0; ct < 4; ++ct)
                        acc[pt][ct] = __builtin_amdgcn_mfma_f32_16x16x32_bf16(
                            af[pt], bf[ct], acc[pt][ct], 0, 0, 0);
            }

            float ccv[4];
#pragma unroll
            for (int ct = 0; ct < 4; ++ct)
                ccv[ct] = ccS[chunk * VCHUNK + wc * 64 + ct * 16 + l15];

            if (pass == 0) {
#pragma unroll
                for (int pt = 0; pt < 4; ++pt)
#pragma unroll
                    for (int r = 0; r < 4; ++r) {
                        float m = fmaf(-2.f, acc[pt][0][r], ccv[0]);
                        m = fminf(m, fmaf(-2.f, acc[pt][1][r], ccv[1]));
                        m = fminf(m, fmaf(-2.f, acc[pt][2][r], ccv[2]));
                        m = fminf(m, fmaf(-2.f, acc[pt][3][r], ccv[3]));
                        mn[pt][r] = fminf(mn[pt][r], m);
                    }
            } else {
#pragma unroll
                for (int pt = 0; pt < 4; ++pt)
#pragma unroll
                    for (int ct = 0; ct < 4; ++ct)
#pragma unroll
                        for (int r = 0; r < 4; ++r) {
                            float d = fmaf(-2.f, acc[pt][ct][r], ccv[ct]);
                            if (d <= thr[pt][r]) {
                                int pos = wr * 64 + pt * 16 + lg * 4 + r;
                                unsigned idx = chunk * VCHUNK + wc * 64 + ct * 16 + l15;
                                unsigned slot = atomicAdd(&cnt[pos], 1u);
                                if (slot < CAP) candI[pos * CAP + slot] = idx;
                            }
                        }
            }
        }

        if (pass == 0) {
            // cross-lane min over the 16 cols (masks 1,2,4,8 stay in lg group)
#pragma unroll
            for (int pt = 0; pt < 4; ++pt)
#pragma unroll
                for (int r = 0; r < 4; ++r) {
#pragma unroll
                    for (int m = 1; m < 16; m <<= 1)
                        mn[pt][r] = fminf(mn[pt][r], __shfl_xor(mn[pt][r], m, 64));
                }
            if (l15 == 0) {
#pragma unroll
                for (int pt = 0; pt < 4; ++pt)
#pragma unroll
                    for (int r = 0; r < 4; ++r)
                        atomicMin(&bestU[wr * 64 + pt * 16 + lg * 4 + r], fkey(mn[pt][r]));
            }
            __syncthreads();
#pragma unroll
            for (int pt = 0; pt < 4; ++pt)
#pragma unroll
                for (int r = 0; r < 4; ++r)
                    thr[pt][r] = funkey(bestU[wr * 64 + pt * 16 + lg * 4 + r]) + MARGIN;
        }
    }
    __syncthreads();

    // ---- np-exact f32 refine of candidates; 16 tcol lanes per pos ----
    {
        const int tcol = tid & 15;
        const int trg  = tid >> 4;
        for (int p = 0; p < 8; ++p) {
            const int pos = p * 16 + trg;
            const float* zp = z + zBase + pos;
            float zloc[64];
#pragma unroll
            for (int k = 0; k < 64; ++k) zloc[k] = zp[(long)k * HW];
            const float zz = zzS[pos];
            const unsigned n = cnt[pos];
            float bd = FLT_MAX; unsigned bi = 0xFFFFFFFFu;
            if (n <= CAP) {
                for (unsigned s = tcol; s < n; s += 16) {
                    unsigned vi = candI[pos * CAP + s];
                    const float4* cr = (const float4*)(cbk + cbBase + (long)vi * DCB);
                    float c[64];
#pragma unroll
                    for (int i = 0; i < 16; ++i) {
                        float4 v = cr[i];
                        c[i * 4 + 0] = v.x; c[i * 4 + 1] = v.y;
                        c[i * 4 + 2] = v.z; c[i * 4 + 3] = v.w;
                    }
                    float d = np_dist(zloc, c, zz, ccS[vi]);
                    if (d < bd || (d == bd && vi < bi)) { bd = d; bi = vi; }
                }
            } else {  // overflow fallback: np-exact rescan of all 1024
                for (unsigned vi = tcol; vi < VOC; vi += 16) {
                    const float4* cr = (const float4*)(cbk + cbBase + (long)vi * DCB);
                    float c[64];
#pragma unroll
                    for (int i = 0; i < 16; ++i) {
                        float4 v = cr[i];
                        c[i * 4 + 0] = v.x; c[i * 4 + 1] = v.y;
                        c[i * 4 + 2] = v.z; c[i * 4 + 3] = v.w;
                    }
                    float d = np_dist(zloc, c, zz, ccS[vi]);
                    if (d < bd || (d == bd && vi < bi)) { bd = d; bi = vi; }
                }
            }
#pragma unroll
            for (int m = 1; m < 16; m <<= 1) {
                float    od = __shfl_xor(bd, m, 64);
                unsigned oi = __shfl_xor(bi, m, 64);
                if (od < bd || (od == bd && oi < bi)) { bd = od; bi = oi; }
            }
            if (tcol == 0) idxF[pos] = bi;
        }
    }
    __syncthreads();

    // ---- indices output ----
    if (tid < POS_TILE) {
        out[Q_ELEMS + (long)b * (NCB * HW) + cb * HW + hw0 + tid] = (float)idxF[tid];
    }

    // ---- epilogue: q gather + straight-through store + commitment ----
    {
        const int pos   = tid & 127;
        const int khalf = tid >> 7;
        const unsigned vi = idxF[pos];
        const float* crow = cbk + cbBase + (long)vi * DCB + khalf * 32;
        const float* zp   = z + zBase + pos + (long)khalf * 32 * HW;
        float* qp = out + (long)b * (DIM * HW) + (long)(cb * DCB + khalf * 32) * HW + hw0 + pos;
        float csum = 0.f;
#pragma unroll
        for (int j4 = 0; j4 < 8; ++j4) {
            float4 cv = *(const float4*)(crow + j4 * 4);
            float z0 = zp[(long)(j4 * 4 + 0) * HW];
            float z1 = zp[(long)(j4 * 4 + 1) * HW];
            float z2 = zp[(long)(j4 * 4 + 2) * HW];
            float z3 = zp[(long)(j4 * 4 + 3) * HW];
            qp[(long)(j4 * 4 + 0) * HW] = (cv.x - z0) + z0;
            qp[(long)(j4 * 4 + 1) * HW] = (cv.y - z1) + z1;
            qp[(long)(j4 * 4 + 2) * HW] = (cv.z - z2) + z2;
            qp[(long)(j4 * 4 + 3) * HW] = (cv.w - z3) + z3;
            float d0 = z0 - cv.x; csum = fmaf(d0, d0, csum);
            float d1 = z1 - cv.y; csum = fmaf(d1, d1, csum);
            float d2 = z2 - cv.z; csum = fmaf(d2, d2, csum);
            float d3 = z3 - cv.w; csum = fmaf(d3, d3, csum);
        }
#pragma unroll
        for (int m = 1; m < 64; m <<= 1) csum += __shfl_xor(csum, m, 64);
        if ((tid & 63) == 0) wred[tid >> 6] = csum;
    }
    __syncthreads();
    if (tid == 0) atomicAdd(commitWs, wred[0] + wred[1] + wred[2] + wred[3]);
}

// ---- K2: finalize commitment scalar ----
__global__ void vq_fin_kernel(const float* __restrict__ ws, float* __restrict__ out) {
    out[C_OFFSET] = ws[0] * (1.0f / 8388608.0f);
}

extern "C" void kernel_launch(void* const* d_in, const int* in_sizes, int n_in,
                              void* d_out, int out_size, void* d_ws, size_t ws_size,
                              hipStream_t stream) {
    (void)in_sizes; (void)n_in; (void)out_size; (void)ws_size;
    const float* z   = (const float*)d_in[0];
    const float* cbk = (const float*)d_in[1];
    float* out   = (float*)d_out;
    float* ws    = (float*)d_ws;       // [0]: commitment accumulator
    float* ccTab = ws + 64;            // 8192 f32 code norms

    hipMemsetAsync(d_ws, 0, 4, stream);
    vq_cc_kernel<<<dim3(32), dim3(256), 0, stream>>>(cbk, ccTab);
    vq_main_kernel<<<dim3(1024), dim3(THREADS), LDS_BYTES, stream>>>(z, cbk, ccTab, ws, out);
    vq_fin_kernel<<<dim3(1), dim3(1), 0, stream>>>(ws, out);
}

// Round 5
// 196.826 us; speedup vs baseline: 2.0636x; 1.2794x over previous
//
#include <hip/hip_runtime.h>
#include <float.h>

// Problem constants
#define DIM   512
#define HW    1024
#define NCB   8
#define VOC   1024
#define DCB   64

#define THREADS   256
#define POS_TILE  128
#define VCHUNK    128
#define NCHUNK    8
#define CAP       16
#define MARGIN    0.012f

#define Q_ELEMS   8388608
#define I_ELEMS   131072
#define C_OFFSET  8519680

// workspace layout (bytes)
// [0] float commit | [4] unsigned doneCnt | [256] float ccTab[8192] | [33024] ushort cbkBf[8*1024*64]
#define WS_CC_OFF 256
#define WS_CB_OFF 33024

typedef __attribute__((ext_vector_type(8))) short          short8;
typedef __attribute__((ext_vector_type(8))) unsigned short ushort8;
typedef __attribute__((ext_vector_type(4))) float          floatx4;

// f32 -> bf16 RNE
__device__ __forceinline__ unsigned short f2bf(float f) {
    unsigned u = __builtin_bit_cast(unsigned, f);
    unsigned r = u + 0x7FFFu + ((u >> 16) & 1u);
    return (unsigned short)(r >> 16);
}

// ===== numpy-f32 emulation (identical arithmetic to round-3/4 PASSING kernels) =====
__device__ __forceinline__ float np_sumsq64(const float v[64]) {
#pragma clang fp contract(off)
    float sq[64];
#pragma unroll
    for (int k = 0; k < 64; ++k) sq[k] = v[k] * v[k];
    float r[8];
#pragma unroll
    for (int j = 0; j < 8; ++j) r[j] = sq[j];
#pragma unroll
    for (int i = 8; i < 64; i += 8)
#pragma unroll
        for (int j = 0; j < 8; ++j) r[j] = r[j] + sq[i + j];
    return ((r[0] + r[1]) + (r[2] + r[3])) + ((r[4] + r[5]) + (r[6] + r[7]));
}

__device__ __forceinline__ float np_dist(const float zloc[64], const float c[64],
                                         float zz, float ccv) {
#pragma clang fp contract(off)
    float p[16];
#pragma unroll
    for (int l = 0; l < 16; ++l) p[l] = 0.f;
#pragma unroll
    for (int j = 0; j < 4; ++j)
#pragma unroll
        for (int l = 0; l < 16; ++l)
            p[l] = __builtin_fmaf(zloc[j * 16 + l], c[j * 16 + l], p[l]);
    float s8[8], s4[4];
#pragma unroll
    for (int l = 0; l < 8; ++l) s8[l] = p[l] + p[l + 8];
#pragma unroll
    for (int l = 0; l < 4; ++l) s4[l] = s8[l] + s8[l + 4];
    float u0 = s4[0] + s4[2];
    float u1 = s4[1] + s4[3];
    float E  = u0 + u1;
    float t  = zz - 2.0f * E;
    return t + ccv;
}

// ---- K0: np-exact code norms + bf16(-2*c) pre-swizzled codebook ----
__global__ __launch_bounds__(256) void vq_prep_kernel(const float* __restrict__ cbk,
                                                      float* __restrict__ cc,
                                                      unsigned short* __restrict__ cbkBf) {
    int t = blockIdx.x * 256 + threadIdx.x;      // 0..8191 = cb*1024 + code
    const float4* row = (const float4*)(cbk + (long)t * DCB);
    float c[64];
#pragma unroll
    for (int i = 0; i < 16; ++i) {
        float4 v = row[i];
        c[i * 4 + 0] = v.x; c[i * 4 + 1] = v.y;
        c[i * 4 + 2] = v.z; c[i * 4 + 3] = v.w;
    }
    cc[t] = np_sumsq64(c);
    const int swz = (t & 7) << 3;
#pragma unroll
    for (int g8 = 0; g8 < 8; ++g8) {
        ushort8 w;
#pragma unroll
        for (int e = 0; e < 8; ++e) w[e] = f2bf(-2.0f * c[g8 * 8 + e]);
        *(ushort8*)&cbkBf[(long)t * 64 + ((g8 * 8) ^ swz)] = w;
    }
}

// LDS
struct SmemT {
    unsigned short zsb[POS_TILE * DCB];      // 16384 B  bf16 z [pos][k^swz]
    unsigned short csb[2][VCHUNK * DCB];     // 32768 B  bf16 -2c, double buffer
    float          ccS[VOC];                 //  4096 B
    unsigned       candI[POS_TILE * CAP];    //  8192 B
    unsigned       cnt[POS_TILE];            //   512 B
    unsigned       idxF[POS_TILE];           //   512 B
    float          wred[4];                  //    16 B
};                                            // 62480 B -> 2 blocks/CU

// async DMA: 16 KB chunk, 4 waves x 4 instr x 1 KB (lane*16B appended by HW)
__device__ __forceinline__ void stage_cb(unsigned short* ldsDst,
                                         const unsigned short* gSrc,
                                         int wid, int lane) {
#pragma unroll
    for (int i = 0; i < 4; ++i) {
        const int off = wid * 2048 + i * 512;            // ushorts
        const unsigned short* g = gSrc + off + lane * 8;
        unsigned short* l = ldsDst + off;
        __builtin_amdgcn_global_load_lds(
            (const __attribute__((address_space(1))) unsigned int*)(const void*)g,
            (__attribute__((address_space(3))) unsigned int*)(void*)l,
            16, 0, 0);
    }
}

// ---- K1: single-pass MFMA scan + np-exact refine + outputs ----
__global__ __launch_bounds__(THREADS, 2) void vq_main_kernel(
    const float* __restrict__ z, const float* __restrict__ cbk,
    const float* __restrict__ ccTab, const unsigned short* __restrict__ cbkBf,
    float* __restrict__ commitWs, unsigned* __restrict__ doneCnt,
    float* __restrict__ out)
{
    __shared__ SmemT sm;

    const int tid   = threadIdx.x;
    const int lane  = tid & 63;
    const int wid   = tid >> 6;            // 4 waves
    const int l15   = lane & 15;
    const int lg    = lane >> 4;           // 0..3
    const int wpos0 = wid * 32;            // wave owns 32 positions
    const int cb    = blockIdx.x & 7;
    const int tile  = blockIdx.x >> 3;
    const int b     = tile >> 3;
    const int hw0   = (tile & 7) * POS_TILE;

    const long zBase  = (long)b * (DIM * HW) + (long)cb * DCB * HW + hw0;
    const long cbBase = (long)cb * (VOC * DCB);
    const unsigned short* cbkBfCb = cbkBf + cbBase;   // same element count

    // prologue: issue chunk-0 DMA first (overlaps the VALU staging below)
    stage_cb(sm.csb[0], cbkBfCb, wid, lane);

    // stage z as bf16 [pos][k ^ (pos&7)<<3], paired writes
    for (int i = 0; i < 16; ++i) {
        int e   = i * THREADS + tid;       // 0..4095
        int kp  = e >> 7;                  // 0..31
        int pos = e & 127;
        int k   = kp * 2;
        float v0 = z[zBase + (long)k * HW + pos];
        float v1 = z[zBase + (long)(k + 1) * HW + pos];
        unsigned pack = (unsigned)f2bf(v0) | ((unsigned)f2bf(v1) << 16);
        *(unsigned*)&sm.zsb[pos * 64 + (k ^ ((pos & 7) << 3))] = pack;
    }
    // stage cc row (4 KB)
    ((float4*)sm.ccS)[tid] = ((const float4*)(ccTab + cb * VOC))[tid];
    if (tid < POS_TILE) sm.cnt[tid] = 0;
    __syncthreads();   // drains vmcnt(0): chunk-0 DMA landed; zsb/ccS visible

    float runBest[2] = {FLT_MAX, FLT_MAX};
    int cur = 0;

    for (int chunk = 0; chunk < NCHUNK; ++chunk) {
        if (chunk < 7)
            stage_cb(sm.csb[cur ^ 1], cbkBfCb + (long)(chunk + 1) * VCHUNK * DCB, wid, lane);

        const unsigned short* cs = sm.csb[cur];

        // acc init = cc[code] -> final acc = cc - 2*dot = dist'
        floatx4 acc[8][2];
#pragma unroll
        for (int ct = 0; ct < 8; ++ct) {
            float4 ci = *(const float4*)&sm.ccS[chunk * VCHUNK + ct * 16 + lg * 4];
            floatx4 a = {ci.x, ci.y, ci.z, ci.w};
            acc[ct][0] = a; acc[ct][1] = a;
        }

#pragma unroll
        for (int ks = 0; ks < 2; ++ks) {
            short8 bz[2];
#pragma unroll
            for (int pt = 0; pt < 2; ++pt) {
                int row = wpos0 + pt * 16 + l15;
                bz[pt] = *(const short8*)&sm.zsb[row * 64 + ((ks * 32 + lg * 8) ^ ((row & 7) << 3))];
            }
#pragma unroll
            for (int ct = 0; ct < 8; ++ct) {
                int crow = ct * 16 + l15;
                short8 ac = *(const short8*)&cs[crow * 64 + ((ks * 32 + lg * 8) ^ ((crow & 7) << 3))];
#pragma unroll
                for (int pt = 0; pt < 2; ++pt)
                    acc[ct][pt] = __builtin_amdgcn_mfma_f32_16x16x32_bf16(ac, bz[pt], acc[ct][pt], 0, 0, 0);
            }
        }

        // per-pos chunk min -> running min -> collect within margin
#pragma unroll
        for (int pt = 0; pt < 2; ++pt) {
            float m = acc[0][pt][0];
#pragma unroll
            for (int ct = 0; ct < 8; ++ct)
#pragma unroll
                for (int r = 0; r < 4; ++r) m = fminf(m, acc[ct][pt][r]);
            m = fminf(m, __shfl_xor(m, 16, 64));
            m = fminf(m, __shfl_xor(m, 32, 64));
            runBest[pt] = fminf(runBest[pt], m);
            const float thr = runBest[pt] + MARGIN;
            const int pos = wpos0 + pt * 16 + l15;
#pragma unroll
            for (int ct = 0; ct < 8; ++ct)
#pragma unroll
                for (int r = 0; r < 4; ++r) {
                    if (acc[ct][pt][r] <= thr) {
                        unsigned idx  = chunk * VCHUNK + ct * 16 + lg * 4 + r;
                        unsigned slot = atomicAdd(&sm.cnt[pos], 1u);
                        if (slot < CAP) sm.candI[pos * CAP + slot] = idx;
                    }
                }
        }
        __syncthreads();   // vmcnt(0): next chunk landed; all reads of cs done
        cur ^= 1;
    }

    // ---- np-exact f32 refine: 1 thread per pos, serial over ~1.6 candidates ----
    if (tid < POS_TILE) {
        const int pos = tid;
        float zloc[64];
#pragma unroll
        for (int k = 0; k < 64; ++k) zloc[k] = z[zBase + (long)k * HW + pos];
        const float zz = np_sumsq64(zloc);
        const unsigned n = sm.cnt[pos];
        float bd = FLT_MAX; unsigned bi = 0xFFFFFFFFu;
        if (n <= CAP) {
            for (unsigned s = 0; s < n; ++s) {
                unsigned vi = sm.candI[pos * CAP + s];
                const float4* cr = (const float4*)(cbk + cbBase + (long)vi * DCB);
                float c[64];
#pragma unroll
                for (int i = 0; i < 16; ++i) {
                    float4 v = cr[i];
                    c[i * 4 + 0] = v.x; c[i * 4 + 1] = v.y;
                    c[i * 4 + 2] = v.z; c[i * 4 + 3] = v.w;
                }
                float d = np_dist(zloc, c, zz, sm.ccS[vi]);
                if (d < bd || (d == bd && vi < bi)) { bd = d; bi = vi; }
            }
        } else {  // overflow fallback (P ~ 1e-12): np-exact rescan, ascending = np order
            for (unsigned vi = 0; vi < VOC; ++vi) {
                const float4* cr = (const float4*)(cbk + cbBase + (long)vi * DCB);
                float c[64];
#pragma unroll
                for (int i = 0; i < 16; ++i) {
                    float4 v = cr[i];
                    c[i * 4 + 0] = v.x; c[i * 4 + 1] = v.y;
                    c[i * 4 + 2] = v.z; c[i * 4 + 3] = v.w;
                }
                float d = np_dist(zloc, c, zz, sm.ccS[vi]);
                if (d < bd) { bd = d; bi = vi; }
            }
        }
        sm.idxF[pos] = bi;
        out[Q_ELEMS + (long)b * (NCB * HW) + cb * HW + hw0 + pos] = (float)bi;
    }
    __syncthreads();

    // ---- epilogue: q gather + straight-through store + commitment ----
    {
        const int pos   = tid & 127;
        const int khalf = tid >> 7;
        const unsigned vi = sm.idxF[pos];
        const float* crow = cbk + cbBase + (long)vi * DCB + khalf * 32;
        const float* zp   = z + zBase + pos + (long)khalf * 32 * HW;
        float* qp = out + (long)b * (DIM * HW) + (long)(cb * DCB + khalf * 32) * HW + hw0 + pos;
        float csum = 0.f;
#pragma unroll
        for (int j4 = 0; j4 < 8; ++j4) {
            float4 cv = *(const float4*)(crow + j4 * 4);
            float z0 = zp[(long)(j4 * 4 + 0) * HW];
            float z1 = zp[(long)(j4 * 4 + 1) * HW];
            float z2 = zp[(long)(j4 * 4 + 2) * HW];
            float z3 = zp[(long)(j4 * 4 + 3) * HW];
            qp[(long)(j4 * 4 + 0) * HW] = (cv.x - z0) + z0;
            qp[(long)(j4 * 4 + 1) * HW] = (cv.y - z1) + z1;
            qp[(long)(j4 * 4 + 2) * HW] = (cv.z - z2) + z2;
            qp[(long)(j4 * 4 + 3) * HW] = (cv.w - z3) + z3;
            float d0 = z0 - cv.x; csum = fmaf(d0, d0, csum);
            float d1 = z1 - cv.y; csum = fmaf(d1, d1, csum);
            float d2 = z2 - cv.z; csum = fmaf(d2, d2, csum);
            float d3 = z3 - cv.w; csum = fmaf(d3, d3, csum);
        }
#pragma unroll
        for (int m = 1; m < 64; m <<= 1) csum += __shfl_xor(csum, m, 64);
        if (lane == 0) sm.wred[wid] = csum;
    }
    __syncthreads();

    if (tid == 0) {
        atomicAdd(commitWs, sm.wred[0] + sm.wred[1] + sm.wred[2] + sm.wred[3]);
        __threadfence();
        unsigned d = atomicAdd(doneCnt, 1u);
        if (d == 1023u) {                       // last block finalizes the scalar
            __threadfence();
            float tot = atomicAdd(commitWs, 0.0f);
            out[C_OFFSET] = tot * (1.0f / 8388608.0f);
        }
    }
}

extern "C" void kernel_launch(void* const* d_in, const int* in_sizes, int n_in,
                              void* d_out, int out_size, void* d_ws, size_t ws_size,
                              hipStream_t stream) {
    (void)in_sizes; (void)n_in; (void)out_size; (void)ws_size;
    const float* z   = (const float*)d_in[0];
    const float* cbk = (const float*)d_in[1];
    float* out = (float*)d_out;
    char*  ws  = (char*)d_ws;
    float*          commitWs = (float*)ws;
    unsigned*       doneCnt  = (unsigned*)(ws + 4);
    float*          ccTab    = (float*)(ws + WS_CC_OFF);
    unsigned short* cbkBf    = (unsigned short*)(ws + WS_CB_OFF);   // needs ws_size >= ~1.1 MB

    hipMemsetAsync(d_ws, 0, 8, stream);
    vq_prep_kernel<<<dim3(32), dim3(256), 0, stream>>>(cbk, ccTab, cbkBf);
    vq_main_kernel<<<dim3(1024), dim3(THREADS), 0, stream>>>(z, cbk, ccTab, cbkBf,
                                                             commitWs, doneCnt, out);
}

// Round 6
// 193.398 us; speedup vs baseline: 2.1002x; 1.0177x over previous
//
#include <hip/hip_runtime.h>
#include <float.h>

// Problem constants
#define DIM   512
#define HW    1024
#define NCB   8
#define VOC   1024
#define DCB   64

#define THREADS   256
#define POS_TILE  128
#define VCHUNK    128
#define NCHUNK    8
#define CAP       16
#define MARGIN    0.012f

#define Q_ELEMS   8388608
#define I_ELEMS   131072
#define C_OFFSET  8519680

// workspace layout (bytes)
// [0] float commit | [4] unsigned doneCnt | [256] float ccTab[8192] | [33024] ushort cbkBf[8*1024*64]
#define WS_CC_OFF 256
#define WS_CB_OFF 33024

typedef __attribute__((ext_vector_type(8))) short          short8;
typedef __attribute__((ext_vector_type(8))) unsigned short ushort8;
typedef __attribute__((ext_vector_type(4))) float          floatx4;

// f32 -> bf16 RNE
__device__ __forceinline__ unsigned short f2bf(float f) {
    unsigned u = __builtin_bit_cast(unsigned, f);
    unsigned r = u + 0x7FFFu + ((u >> 16) & 1u);
    return (unsigned short)(r >> 16);
}

// ---- K0: np-exact code norms + bf16(-2*c) pre-swizzled codebook ----
// 64 blocks x 128 threads; streamed sumsq (same FP ops/order as validated np_sumsq64)
__global__ __launch_bounds__(128) void vq_prep_kernel(const float* __restrict__ cbk,
                                                      char* __restrict__ ws,
                                                      float* __restrict__ cc,
                                                      unsigned short* __restrict__ cbkBf) {
#pragma clang fp contract(off)
    int t = blockIdx.x * 128 + threadIdx.x;      // 0..8191 = cb*1024 + code
    if (t == 0) { ((float*)ws)[0] = 0.f; ((unsigned*)ws)[1] = 0u; }
    const float4* row = (const float4*)(cbk + (long)t * DCB);
    float c[64];
#pragma unroll
    for (int i = 0; i < 16; ++i) {
        float4 v = row[i];
        c[i * 4 + 0] = v.x; c[i * 4 + 1] = v.y;
        c[i * 4 + 2] = v.z; c[i * 4 + 3] = v.w;
    }
    float r[8];
#pragma unroll
    for (int j = 0; j < 8; ++j) { float sq = c[j] * c[j]; r[j] = sq; }
#pragma unroll
    for (int i = 1; i < 8; ++i)
#pragma unroll
        for (int j = 0; j < 8; ++j) { float sq = c[i * 8 + j] * c[i * 8 + j]; r[j] = r[j] + sq; }
    cc[t] = ((r[0] + r[1]) + (r[2] + r[3])) + ((r[4] + r[5]) + (r[6] + r[7]));
    const int swz = (t & 7) << 3;
#pragma unroll
    for (int g8 = 0; g8 < 8; ++g8) {
        ushort8 w;
#pragma unroll
        for (int e = 0; e < 8; ++e) w[e] = f2bf(-2.0f * c[g8 * 8 + e]);
        *(ushort8*)&cbkBf[(long)t * 64 + ((g8 * 8) ^ swz)] = w;
    }
}

// LDS
struct SmemT {
    unsigned short zsb[POS_TILE * DCB];      // 16384 B  bf16 z [pos][k^swz]
    unsigned short csb[2][VCHUNK * DCB];     // 32768 B  bf16 -2c dbuf; reused post-scan as f32 z[64][128]
    float          ccS[VOC];                 //  4096 B
    unsigned       candI[POS_TILE * CAP];    //  8192 B
    unsigned       cnt[POS_TILE];            //   512 B
    unsigned       idxF[POS_TILE];           //   512 B
    float          wred[4];                  //    16 B
};                                            // 62480 B -> 2 blocks/CU

// async DMA: 16 KB chunk, 4 waves x 4 instr x 1 KB
__device__ __forceinline__ void stage_cb(unsigned short* ldsDst,
                                         const unsigned short* gSrc,
                                         int wid, int lane) {
#pragma unroll
    for (int i = 0; i < 4; ++i) {
        const int off = wid * 2048 + i * 512;            // ushorts
        const unsigned short* g = gSrc + off + lane * 8;
        unsigned short* l = ldsDst + off;
        __builtin_amdgcn_global_load_lds(
            (const __attribute__((address_space(1))) unsigned int*)(const void*)g,
            (__attribute__((address_space(3))) unsigned int*)(void*)l,
            16, 0, 0);
    }
}

// streamed np einsum-dist: d = (zz - 2*E) + cc, E via 16-lane FMA + tree.
// zcol: f32 z column (stride 128); cr: code row as float4*.
__device__ __forceinline__ float np_dist_stream(const float* zcol, const float4* cr,
                                                float zz, float ccv) {
#pragma clang fp contract(off)
    float p[16];
#pragma unroll
    for (int l = 0; l < 16; ++l) p[l] = 0.f;
#pragma unroll
    for (int j = 0; j < 4; ++j) {
        float4 c0 = cr[j * 4 + 0], c1 = cr[j * 4 + 1];
        float4 c2 = cr[j * 4 + 2], c3 = cr[j * 4 + 3];
        float cl[16] = {c0.x, c0.y, c0.z, c0.w, c1.x, c1.y, c1.z, c1.w,
                        c2.x, c2.y, c2.z, c2.w, c3.x, c3.y, c3.z, c3.w};
#pragma unroll
        for (int l = 0; l < 16; ++l)
            p[l] = __builtin_fmaf(zcol[(long)(j * 16 + l) * POS_TILE], cl[l], p[l]);
    }
    float s8[8], s4[4];
#pragma unroll
    for (int l = 0; l < 8; ++l) s8[l] = p[l] + p[l + 8];
#pragma unroll
    for (int l = 0; l < 4; ++l) s4[l] = s8[l] + s8[l + 4];
    float u0 = s4[0] + s4[2];
    float u1 = s4[1] + s4[3];
    float E  = u0 + u1;
    float t  = zz - 2.0f * E;
    return t + ccv;
}

// ---- K1: single-pass MFMA scan + np-exact refine + outputs ----
__global__ __launch_bounds__(THREADS, 2) void vq_main_kernel(
    const float* __restrict__ z, const float* __restrict__ cbk,
    const float* __restrict__ ccTab, const unsigned short* __restrict__ cbkBf,
    float* __restrict__ commitWs, unsigned* __restrict__ doneCnt,
    float* __restrict__ out)
{
    __shared__ SmemT sm;

    const int tid   = threadIdx.x;
    const int lane  = tid & 63;
    const int wid   = tid >> 6;            // 4 waves
    const int l15   = lane & 15;
    const int lg    = lane >> 4;           // 0..3
    const int wpos0 = wid * 32;            // wave owns 32 positions
    const int cb    = blockIdx.x & 7;      // == XCD id under %8 round-robin: per-XCD L2 holds its own codebook
    const int tile  = blockIdx.x >> 3;
    const int b     = tile >> 3;
    const int hw0   = (tile & 7) * POS_TILE;

    const long zBase  = (long)b * (DIM * HW) + (long)cb * DCB * HW + hw0;
    const long cbBase = (long)cb * (VOC * DCB);
    const unsigned short* cbkBfCb = cbkBf + cbBase;

    // prologue: issue chunk-0 DMA first (overlaps the VALU staging below)
    stage_cb(sm.csb[0], cbkBfCb, wid, lane);

    // stage z as bf16 [pos][k ^ (pos&7)<<3], paired writes
    for (int i = 0; i < 16; ++i) {
        int e   = i * THREADS + tid;       // 0..4095
        int kp  = e >> 7;                  // 0..31
        int pos = e & 127;
        int k   = kp * 2;
        float v0 = z[zBase + (long)k * HW + pos];
        float v1 = z[zBase + (long)(k + 1) * HW + pos];
        unsigned pack = (unsigned)f2bf(v0) | ((unsigned)f2bf(v1) << 16);
        *(unsigned*)&sm.zsb[pos * 64 + (k ^ ((pos & 7) << 3))] = pack;
    }
    // stage cc row (4 KB)
    ((float4*)sm.ccS)[tid] = ((const float4*)(ccTab + cb * VOC))[tid];
    if (tid < POS_TILE) sm.cnt[tid] = 0;
    __syncthreads();   // drains vmcnt(0): chunk-0 DMA landed; zsb/ccS visible

    float runBest[2] = {FLT_MAX, FLT_MAX};
    int cur = 0;

    for (int chunk = 0; chunk < NCHUNK; ++chunk) {
        if (chunk < 7)
            stage_cb(sm.csb[cur ^ 1], cbkBfCb + (long)(chunk + 1) * VCHUNK * DCB, wid, lane);

        const unsigned short* cs = sm.csb[cur];

        // acc init = cc[code] -> final acc = cc - 2*dot = dist'
        floatx4 acc[8][2];
#pragma unroll
        for (int ct = 0; ct < 8; ++ct) {
            float4 ci = *(const float4*)&sm.ccS[chunk * VCHUNK + ct * 16 + lg * 4];
            floatx4 a = {ci.x, ci.y, ci.z, ci.w};
            acc[ct][0] = a; acc[ct][1] = a;
        }

#pragma unroll
        for (int ks = 0; ks < 2; ++ks) {
            short8 bz[2];
#pragma unroll
            for (int pt = 0; pt < 2; ++pt) {
                int row = wpos0 + pt * 16 + l15;
                bz[pt] = *(const short8*)&sm.zsb[row * 64 + ((ks * 32 + lg * 8) ^ ((row & 7) << 3))];
            }
#pragma unroll
            for (int ct = 0; ct < 8; ++ct) {
                int crow = ct * 16 + l15;
                short8 ac = *(const short8*)&cs[crow * 64 + ((ks * 32 + lg * 8) ^ ((crow & 7) << 3))];
#pragma unroll
                for (int pt = 0; pt < 2; ++pt)
                    acc[ct][pt] = __builtin_amdgcn_mfma_f32_16x16x32_bf16(ac, bz[pt], acc[ct][pt], 0, 0, 0);
            }
        }

        // per-pos chunk min -> running min -> collect within margin
#pragma unroll
        for (int pt = 0; pt < 2; ++pt) {
            float m = acc[0][pt][0];
#pragma unroll
            for (int ct = 0; ct < 8; ++ct)
#pragma unroll
                for (int r = 0; r < 4; ++r) m = fminf(m, acc[ct][pt][r]);
            m = fminf(m, __shfl_xor(m, 16, 64));
            m = fminf(m, __shfl_xor(m, 32, 64));
            runBest[pt] = fminf(runBest[pt], m);
            const float thr = runBest[pt] + MARGIN;
            const int pos = wpos0 + pt * 16 + l15;
#pragma unroll
            for (int ct = 0; ct < 8; ++ct)
#pragma unroll
                for (int r = 0; r < 4; ++r) {
                    if (acc[ct][pt][r] <= thr) {
                        unsigned idx  = chunk * VCHUNK + ct * 16 + lg * 4 + r;
                        unsigned slot = atomicAdd(&sm.cnt[pos], 1u);
                        if (slot < CAP) sm.candI[pos * CAP + slot] = idx;
                    }
                }
        }
        __syncthreads();   // vmcnt(0): next chunk landed; all reads of cs done
        cur ^= 1;
    }

    // ---- restage f32 z into the (now dead) csb region: zf32[k][pos] ----
    float* zf32 = (float*)sm.csb;
#pragma unroll
    for (int i = 0; i < 8; ++i) {
        int e4   = i * THREADS + tid;      // 0..2047 float4s
        int k    = e4 >> 5;
        int posq = e4 & 31;
        float4 v = *(const float4*)(z + zBase + (long)k * HW + posq * 4);
        *(float4*)&zf32[k * POS_TILE + posq * 4] = v;
    }
    __syncthreads();

    // ---- np-exact f32 refine: 1 thread per pos, streamed (no spills) ----
    if (tid < POS_TILE) {
        const int pos = tid;
        const float* zcol = zf32 + pos;
        float zz;
        {
#pragma clang fp contract(off)
            float r[8];
#pragma unroll
            for (int j = 0; j < 8; ++j) { float v = zcol[(long)j * POS_TILE]; r[j] = v * v; }
#pragma unroll
            for (int i = 1; i < 8; ++i)
#pragma unroll
                for (int j = 0; j < 8; ++j) {
                    float v = zcol[(long)(i * 8 + j) * POS_TILE];
                    r[j] = r[j] + v * v;
                }
            zz = ((r[0] + r[1]) + (r[2] + r[3])) + ((r[4] + r[5]) + (r[6] + r[7]));
        }
        const unsigned n = sm.cnt[pos];
        float bd = FLT_MAX; unsigned bi = 0xFFFFFFFFu;
        if (n <= CAP) {
            for (unsigned s = 0; s < n; ++s) {
                unsigned vi = sm.candI[pos * CAP + s];
                float d = np_dist_stream(zcol, (const float4*)(cbk + cbBase + (long)vi * DCB),
                                         zz, sm.ccS[vi]);
                if (d < bd || (d == bd && vi < bi)) { bd = d; bi = vi; }
            }
        } else {  // overflow fallback (P ~ 1e-12): np-exact rescan, ascending = np order
            for (unsigned vi = 0; vi < VOC; ++vi) {
                float d = np_dist_stream(zcol, (const float4*)(cbk + cbBase + (long)vi * DCB),
                                         zz, sm.ccS[vi]);
                if (d < bd) { bd = d; bi = vi; }
            }
        }
        sm.idxF[pos] = bi;
        out[Q_ELEMS + (long)b * (NCB * HW) + cb * HW + hw0 + pos] = (float)bi;
    }
    __syncthreads();

    // ---- epilogue: q gather + straight-through store + commitment (z from LDS) ----
    {
        const int pos   = tid & 127;
        const int khalf = tid >> 7;
        const unsigned vi = sm.idxF[pos];
        const float* crow = cbk + cbBase + (long)vi * DCB + khalf * 32;
        const float* zcol = zf32 + pos + khalf * 32 * POS_TILE;
        float* qp = out + (long)b * (DIM * HW) + (long)(cb * DCB + khalf * 32) * HW + hw0 + pos;
        float csum = 0.f;
#pragma unroll
        for (int j4 = 0; j4 < 8; ++j4) {
            float4 cv = *(const float4*)(crow + j4 * 4);
            float z0 = zcol[(j4 * 4 + 0) * POS_TILE];
            float z1 = zcol[(j4 * 4 + 1) * POS_TILE];
            float z2 = zcol[(j4 * 4 + 2) * POS_TILE];
            float z3 = zcol[(j4 * 4 + 3) * POS_TILE];
            qp[(long)(j4 * 4 + 0) * HW] = (cv.x - z0) + z0;
            qp[(long)(j4 * 4 + 1) * HW] = (cv.y - z1) + z1;
            qp[(long)(j4 * 4 + 2) * HW] = (cv.z - z2) + z2;
            qp[(long)(j4 * 4 + 3) * HW] = (cv.w - z3) + z3;
            float d0 = z0 - cv.x; csum = fmaf(d0, d0, csum);
            float d1 = z1 - cv.y; csum = fmaf(d1, d1, csum);
            float d2 = z2 - cv.z; csum = fmaf(d2, d2, csum);
            float d3 = z3 - cv.w; csum = fmaf(d3, d3, csum);
        }
#pragma unroll
        for (int m = 1; m < 64; m <<= 1) csum += __shfl_xor(csum, m, 64);
        if (lane == 0) sm.wred[wid] = csum;
    }
    __syncthreads();

    if (tid == 0) {
        atomicAdd(commitWs, sm.wred[0] + sm.wred[1] + sm.wred[2] + sm.wred[3]);
        __threadfence();
        unsigned d = atomicAdd(doneCnt, 1u);
        if (d == 1023u) {                       // last block finalizes the scalar
            __threadfence();
            float tot = atomicAdd(commitWs, 0.0f);
            out[C_OFFSET] = tot * (1.0f / 8388608.0f);
        }
    }
}

extern "C" void kernel_launch(void* const* d_in, const int* in_sizes, int n_in,
                              void* d_out, int out_size, void* d_ws, size_t ws_size,
                              hipStream_t stream) {
    (void)in_sizes; (void)n_in; (void)out_size; (void)ws_size;
    const float* z   = (const float*)d_in[0];
    const float* cbk = (const float*)d_in[1];
    float* out = (float*)d_out;
    char*  ws  = (char*)d_ws;
    float*          commitWs = (float*)ws;
    unsigned*       doneCnt  = (unsigned*)(ws + 4);
    float*          ccTab    = (float*)(ws + WS_CC_OFF);
    unsigned short* cbkBf    = (unsigned short*)(ws + WS_CB_OFF);   // needs ws_size >= ~1.1 MB

    vq_prep_kernel<<<dim3(64), dim3(128), 0, stream>>>(cbk, ws, ccTab, cbkBf);
    vq_main_kernel<<<dim3(1024), dim3(THREADS), 0, stream>>>(z, cbk, ccTab, cbkBf,
                                                             commitWs, doneCnt, out);
}